// Round 3
// baseline (392.468 us; speedup 1.0000x reference)
//
#include <hip/hip_runtime.h>
#include <stdint.h>

// ---------------------------------------------------------------------------
// ProteinFeaturesNA on MI355X.
// Outputs (FLOAT32, concatenated): V[512][128], E[15360][128], E_idx[15360].
//
//  kA: augment atoms (Cb, N_na), aug masks, Xc=Ca+na_ref, V layernorm.
//  kB: top-30 neighbors per residue (packed u64 (distbits<<32)|idx, wave min).
//  kW: W_edge fp32 -> bf16, swizzled into MFMA B-fragment order.
//  kC: fused feature-gen (bf16 into LDS) + 16x16x32 bf16 MFMA, M-tile=64,
//      512 thr (8 waves x 1 n-tile), full K in registers, fused layernorm.
//
// ws usage: 3,057,664 bytes.
// ---------------------------------------------------------------------------

#define NRES   512
#define TOPK   30
#define NATOM  26
#define KTOT   10832          // 16 positional + 676*16 RBF
#define NCHUNK 339            // K chunks of 32 (K padded to 10848)
#define MTOT   (NRES*TOPK)    // 15360
#define NOUT   128
#define MT     64             // kC rows per block
#define NBLK   (MTOT/MT)      // 240

#define OFF_AUGX   0u          // 512*26*3 f32   = 159744 B
#define OFF_AUGXM  159744u     // 512*26 f32     =  53248 B
#define OFF_XC     212992u     // 512*3 f32      =   6144 B
#define OFF_EIDX   219136u     // 512*30 i32     =  61440 B
#define OFF_WSWZ   280576u     // 339*512 frag * 16 B = 2777088 B -> end 3057664

#define OUT_V     0
#define OUT_E     (NRES*NOUT)            // 65536
#define OUT_EIDX  (OUT_E + MTOT*NOUT)    // 2031616

typedef __attribute__((ext_vector_type(8))) short bf16x8;
typedef __attribute__((ext_vector_type(4))) float f32x4;

__device__ __forceinline__ unsigned short f2bf(float f) {
    unsigned u = __builtin_bit_cast(unsigned, f);
    return (unsigned short)((u + 0x7fffu + ((u >> 16) & 1u)) >> 16);
}

__device__ __forceinline__ unsigned long long shfl_xor_u64(unsigned long long v, int m) {
    unsigned lo = (unsigned)v, hi = (unsigned)(v >> 32);
    lo = (unsigned)__shfl_xor((int)lo, m, 64);
    hi = (unsigned)__shfl_xor((int)hi, m, 64);
    return ((unsigned long long)hi << 32) | lo;
}

// ---------------------------------------------------------------- kernel A --
__global__ __launch_bounds__(128) void kA(
    const float* __restrict__ X, const float* __restrict__ Xm,
    const float* __restrict__ prot, const float* __restrict__ dna,
    const float* __restrict__ rna, const int* __restrict__ ptype,
    const float* __restrict__ Wn, const float* __restrict__ gn,
    const float* __restrict__ bn, char* __restrict__ ws,
    float* __restrict__ out)
{
    const int i = blockIdx.x, t = threadIdx.x;
    float* augX  = (float*)(ws + OFF_AUGX);
    float* augXm = (float*)(ws + OFF_AUGXM);
    float* Xc    = (float*)(ws + OFF_XC);
    const float* Xi = X + i * 24 * 3;

    if (t < 78) {
        int a = t / 3, c = t - a * 3;
        float v;
        if (a < 24) {
            v = Xi[a * 3 + c];
        } else if (a == 24) {
            // Cb from N(0), Ca(1), C(2)
            float b0 = Xi[3+0]-Xi[0], b1 = Xi[3+1]-Xi[1], b2 = Xi[3+2]-Xi[2];
            float c0 = Xi[6+0]-Xi[3+0], c1 = Xi[6+1]-Xi[3+1], c2 = Xi[6+2]-Xi[3+2];
            float cr0 = b1*c2 - b2*c1, cr1 = b2*c0 - b0*c2, cr2 = b0*c1 - b1*c0;
            float cr = (c==0)?cr0:((c==1)?cr1:cr2);
            float bb = (c==0)?b0:((c==1)?b1:b2);
            float cc = (c==0)?c0:((c==1)?c1:c2);
            v = -0.58273431f*cr + 0.56802827f*bb + -0.54067466f*cc + Xi[3+c];
        } else {
            // N_na from O4P(11), C1P(15), C2P(14)
            const float* O4 = Xi + 11*3; const float* C1 = Xi + 15*3; const float* C2 = Xi + 14*3;
            float b0 = C1[0]-O4[0], b1 = C1[1]-O4[1], b2 = C1[2]-O4[2];
            float c0 = C2[0]-C1[0], c1 = C2[1]-C1[1], c2 = C2[2]-C1[2];
            float cr0 = b1*c2 - b2*c1, cr1 = b2*c0 - b0*c2, cr2 = b0*c1 - b1*c0;
            float cr = (c==0)?cr0:((c==1)?cr1:cr2);
            float bb = (c==0)?b0:((c==1)?b1:b2);
            float cc = (c==0)?c0:((c==1)?c1:c2);
            v = -0.56967352f*cr + 0.51055973f*bb + -0.53122153f*cc + C1[c];
        }
        augX[(i * NATOM + a) * 3 + c] = v;
    } else if (t < 104) {
        int a = t - 78;
        float v = (a < 24) ? Xm[i*24 + a] : ((a == 24) ? prot[i] : dna[i] + rna[i]);
        augXm[i * NATOM + a] = v;
    } else if (t < 107) {
        int c = t - 104;
        Xc[i*3 + c] = Xi[3 + c] + Xi[15*3 + c];   // Ca + na_ref (C1')
    }

    // V = layernorm(W_node[:, type]) over 128 channels
    __shared__ float red[4];
    int ty = ptype[i];
    float v = Wn[t * 3 + ty];
    float s = v;
    #pragma unroll
    for (int off = 32; off; off >>= 1) s += __shfl_xor(s, off, 64);
    if ((t & 63) == 0) red[t >> 6] = s;
    __syncthreads();
    float mean = (red[0] + red[1]) * (1.0f / 128.0f);
    float d = v - mean;
    float s2 = d * d;
    #pragma unroll
    for (int off = 32; off; off >>= 1) s2 += __shfl_xor(s2, off, 64);
    if ((t & 63) == 0) red[2 + (t >> 6)] = s2;
    __syncthreads();
    float var = (red[2] + red[3]) * (1.0f / 128.0f);
    float res = d * rsqrtf(var + 1e-5f) * gn[t] + bn[t];
    out[OUT_V + i * NOUT + t] = res;
}

// ---------------------------------------------------------------- kernel B --
__global__ __launch_bounds__(64) void kB(char* __restrict__ ws,
                                         float* __restrict__ out)
{
    const int i = blockIdx.x, l = threadIdx.x;
    const float* Xc = (const float*)(ws + OFF_XC);
    int* Eidx = (int*)(ws + OFF_EIDX);
    float xi0 = Xc[i*3], xi1 = Xc[i*3+1], xi2 = Xc[i*3+2];
    unsigned long long cand[8];
    #pragma unroll
    for (int s = 0; s < 8; s++) {
        int j = s * 64 + l;
        float dx = xi0 - Xc[j*3], dy = xi1 - Xc[j*3+1], dz = xi2 - Xc[j*3+2];
        float dd = __fadd_rn(__fadd_rn(__fadd_rn(__fmul_rn(dx,dx), __fmul_rn(dy,dy)),
                                       __fmul_rn(dz,dz)), 1e-6f);
        float D = sqrtf(dd);
        cand[s] = ((unsigned long long)__builtin_bit_cast(unsigned, D) << 32) | (unsigned)j;
    }
    for (int m = 0; m < TOPK; m++) {
        unsigned long long k = cand[0];
        #pragma unroll
        for (int s = 1; s < 8; s++) if (cand[s] < k) k = cand[s];
        #pragma unroll
        for (int off = 32; off; off >>= 1) {
            unsigned long long o = shfl_xor_u64(k, off);
            if (o < k) k = o;
        }
        if (l == 0) {
            int j = (int)(k & 0xffffffffu);
            Eidx[i * TOPK + m] = j;
            out[OUT_EIDX + i * TOPK + m] = (float)j;
        }
        #pragma unroll
        for (int s = 0; s < 8; s++) if (cand[s] == k) cand[s] = ~0ull;
    }
}

// ---------------------------------------------------------------- kernel W --
// frag f = (kc*8 + nt)*64 + lane holds W[o = nt*16 + (lane&15)]
//                                      [kc*32 + (lane>>4)*8 + j], j=0..7, bf16
__global__ __launch_bounds__(256) void kW(const float* __restrict__ We,
                                          char* __restrict__ ws)
{
    int f = blockIdx.x * 256 + threadIdx.x;           // 678*256 == 339*512 exact
    int lane = f & 63, nt = (f >> 6) & 7, kc = f >> 9;
    int o  = nt * 16 + (lane & 15);
    int kb = kc * 32 + (lane >> 4) * 8;
    unsigned short tmp[8];
    #pragma unroll
    for (int j = 0; j < 8; j++) {
        int k = kb + j;
        float v = (k < KTOT) ? We[(size_t)o * KTOT + k] : 0.0f;
        tmp[j] = f2bf(v);
    }
    *(uint4*)((unsigned short*)(ws + OFF_WSWZ) + (size_t)f * 8) = *(uint4*)tmp;
}

// ---------------------------------------------------------------- kernel C --
// M-tile 64, 512 threads = 8 waves; wave w owns n-tile w (16 output channels).
// Full K in registers (acc[4] per wave), fused layernorm, f32 store.
__global__ __launch_bounds__(512) void kC(const int* __restrict__ Ridx,
                                          const int* __restrict__ chain,
                                          const float* __restrict__ Wp,
                                          const float* __restrict__ bp,
                                          const float* __restrict__ ge,
                                          const float* __restrict__ be,
                                          char* __restrict__ ws,
                                          float* __restrict__ out)
{
    const int mb = blockIdx.x;
    const int t = threadIdx.x, lane = t & 63, w = t >> 6;
    const int mlane = lane & 15, qd = lane >> 4;
    const float* augX  = (const float*)(ws + OFF_AUGX);
    const float* augXm = (const float*)(ws + OFF_AUGXM);
    const int*   Eidx  = (const int*)(ws + OFF_EIDX);
    const uint4* Wswz  = (const uint4*)(ws + OFF_WSWZ);

    __shared__ float Xjs[3 * NATOM * MT];                      // 19968 B
    __shared__ float Xmjs[NATOM * MT];                         //  6656 B
    __shared__ __align__(16) unsigned short Atile[2][MT * 40]; // 10240 B (80B rows)
    __shared__ int   Jrow[MT];                                 //   256 B
    __shared__ float lnS[8][MT], lnQ[8][MT];                   //  4096 B

    const int r  = lane;                 // every wave covers all 64 rows
    const int rg = mb * MT + r;
    const int i  = rg / TOPK;

    if (t < MT) Jrow[t] = Eidx[mb * MT + t];
    __syncthreads();

    for (int wk = t; wk < NATOM * MT; wk += 512) {
        int a = wk >> 6, rr = wk & 63;
        int jj = Jrow[rr];
        Xmjs[a * MT + rr] = augXm[jj * NATOM + a];
        const float* p = augX + (jj * NATOM + a) * 3;
        Xjs[(0 * NATOM + a) * MT + rr] = p[0];
        Xjs[(1 * NATOM + a) * MT + rr] = p[1];
        Xjs[(2 * NATOM + a) * MT + rr] = p[2];
    }

    const float* xib = augX + i * NATOM * 3;
    const float* mib = augXm + i * NATOM;
    int dcode;
    {
        int j = Jrow[r];
        int off = Ridx[i] - Ridx[j];
        int same = (chain[i] == chain[j]);
        int dc = off + 32; dc = dc < 0 ? 0 : (dc > 64 ? 64 : dc);
        dcode = same ? dc : 65;
    }

    const int h = w >> 2, fq = w & 3;     // unit-half + feature quad per wave
    const float geo = ge[w * 16 + mlane];
    const float beo = be[w * 16 + mlane];

    f32x4 acc[4];
    #pragma unroll
    for (int mt = 0; mt < 4; mt++) acc[mt] = (f32x4){0.f, 0.f, 0.f, 0.f};

    const uint4* Wb = Wswz + (size_t)w * 64 + lane;

    __syncthreads();   // staging visible

    // exp(-((D-mu)/sigma)^2) == exp2(-(D*SA - mu*SA)^2), SA = sqrt(log2 e)/1.25
    const float SA  = 0.96089792702915984f;
    const float MU0 = 1.9217958540583197f;     // 2*SA
    const float MUS = 1.2811972360388798f;     // (4/3)*SA

    for (int kc = 0; kc < NCHUNK; kc++) {
        uint4 bq = Wb[(size_t)kc * 512];        // B fragment (L2-resident)

        const int U = kc * 2 + h;               // wave-uniform feature unit
        float val[4];
        if (U == 0) {
            #pragma unroll
            for (int f = 0; f < 4; f++)
                val[f] = Wp[(fq * 4 + f) * 66 + dcode] + bp[fq * 4 + f];
        } else if (U <= 676) {
            int p  = U - 1;
            int a  = p / NATOM;
            int a2 = p - a * NATOM;
            float mi = mib[a];
            float x0 = xib[a*3], x1 = xib[a*3+1], x2 = xib[a*3+2];
            float mj = Xmjs[a2 * MT + r];
            float dx = x0 - Xjs[(0*NATOM + a2) * MT + r];
            float dy = x1 - Xjs[(1*NATOM + a2) * MT + r];
            float dz = x2 - Xjs[(2*NATOM + a2) * MT + r];
            float D  = sqrtf(dx*dx + dy*dy + dz*dz + 1e-6f);
            float s  = mi * mj;
            float Ds = D * SA;
            #pragma unroll
            for (int f = 0; f < 4; f++) {
                float v = Ds - (MU0 + (float)(fq * 4 + f) * MUS);
                val[f] = exp2f(-v * v) * s;
            }
        } else {
            #pragma unroll
            for (int f = 0; f < 4; f++) val[f] = 0.0f;
        }
        uint2 pk;
        pk.x = (unsigned)f2bf(val[0]) | ((unsigned)f2bf(val[1]) << 16);
        pk.y = (unsigned)f2bf(val[2]) | ((unsigned)f2bf(val[3]) << 16);
        *(uint2*)&Atile[kc & 1][r * 40 + h * 16 + fq * 4] = pk;
        __syncthreads();

        bf16x8 bb = __builtin_bit_cast(bf16x8, bq);
        const unsigned short* At = Atile[kc & 1];
        #pragma unroll
        for (int mt = 0; mt < 4; mt++) {
            bf16x8 af = *(const bf16x8*)&At[(mt * 16 + mlane) * 40 + qd * 8];
            acc[mt] = __builtin_amdgcn_mfma_f32_16x16x32_bf16(af, bb, acc[mt], 0, 0, 0);
        }
    }

    // ---- fused layernorm over 128 channels (8 waves x 16 mlane) ----
    #pragma unroll
    for (int mt = 0; mt < 4; mt++) {
        #pragma unroll
        for (int rr = 0; rr < 4; rr++) {
            float x = acc[mt][rr];
            float xs = x, xq = x * x;
            #pragma unroll
            for (int m = 1; m < 16; m <<= 1) {
                xs += __shfl_xor(xs, m, 64);
                xq += __shfl_xor(xq, m, 64);
            }
            if (mlane == 0) {
                int row = mt * 16 + qd * 4 + rr;
                lnS[w][row] = xs; lnQ[w][row] = xq;
            }
        }
    }
    __syncthreads();
    #pragma unroll
    for (int mt = 0; mt < 4; mt++) {
        #pragma unroll
        for (int rr = 0; rr < 4; rr++) {
            int row = mt * 16 + qd * 4 + rr;
            float S = 0.f, Q = 0.f;
            #pragma unroll
            for (int ww = 0; ww < 8; ww++) { S += lnS[ww][row]; Q += lnQ[ww][row]; }
            float mean = S * (1.0f / 128.0f);
            float var  = Q * (1.0f / 128.0f) - mean * mean;
            float rstd = rsqrtf(var + 1e-5f);
            float res  = (acc[mt][rr] - mean) * rstd * geo + beo;
            out[OUT_E + (size_t)(mb * MT + row) * NOUT + w * 16 + mlane] = res;
        }
    }
}

// ------------------------------------------------------------------- launch --
extern "C" void kernel_launch(void* const* d_in, const int* in_sizes, int n_in,
                              void* d_out, int out_size, void* d_ws, size_t ws_size,
                              hipStream_t stream)
{
    const float* X     = (const float*)d_in[0];
    const int*   Ridx  = (const int*)d_in[2];
    const int*   chain = (const int*)d_in[3];
    const float* Xm    = (const float*)d_in[4];
    const float* prot  = (const float*)d_in[5];
    const float* dna   = (const float*)d_in[6];
    const float* rna   = (const float*)d_in[7];
    const int*   ptype = (const int*)d_in[8];
    const float* Wp    = (const float*)d_in[9];
    const float* bp    = (const float*)d_in[10];
    const float* We    = (const float*)d_in[11];
    const float* Wn    = (const float*)d_in[12];
    const float* ge    = (const float*)d_in[13];
    const float* be    = (const float*)d_in[14];
    const float* gn    = (const float*)d_in[15];
    const float* bn    = (const float*)d_in[16];
    char* ws = (char*)d_ws;
    float* out = (float*)d_out;

    kW<<<dim3(678), dim3(256), 0, stream>>>(We, ws);
    kA<<<dim3(NRES), dim3(128), 0, stream>>>(X, Xm, prot, dna, rna, ptype, Wn, gn, bn, ws, out);
    kB<<<dim3(NRES), dim3(64), 0, stream>>>(ws, out);
    kC<<<dim3(NBLK), dim3(512), 0, stream>>>(Ridx, chain, Wp, bp, ge, be, ws, out);
}

// Round 4
// 293.070 us; speedup vs baseline: 1.3392x; 1.3392x over previous
//
#include <hip/hip_runtime.h>
#include <stdint.h>

// ---------------------------------------------------------------------------
// ProteinFeaturesNA on MI355X — R4: register-A fp8 MFMA, K-split-2.
// Outputs (f32, concat): V[512][128], E[15360][128], E_idx[15360].
//
//  kA: aug atoms -> float4 (x,y,z,mask) + bf16 atom-PAIR table, Xc, V-LN.
//  kB: top-30 neighbors (packed u64 wave min) -> Eidx + out.
//  kW: W_edge -> fp8 B-fragments, unit-slot order: slots 0..675 = RBF unit,
//      676 = positional, 677..679 = zero. dcp d covers slots 4d..4d+3:
//      chunk cc in {0,1}, lane-half h: slot = 4d + 2h + cc  (lane's two
//      slots are consecutive -> same i-atom, adjacent j-atom pair).
//  kC: 256 thr / 4 waves, 32 rows, K-half per blockIdx.y. A-frags generated
//      in registers (1 D + 8 exp2 per chunk per lane), B double-buffered in
//      LDS (16 KB), 8 fp8 MFMAs per 64-k step. f32 partials to ws.
//  kD: partial reduce + layernorm -> E.
// ---------------------------------------------------------------------------

#define NRES   512
#define TOPK   30
#define NATOM  26
#define KTOT   10832
#define NDCP   170            // 64-k double-chunks (padded K = 10880)
#define MTOT   (NRES*TOPK)    // 15360
#define NOUT   128
#define MB     32             // rows per kC block
#define KSPLIT 2
#define DPB    (NDCP/KSPLIT)  // 85

#define OFF_AUGX4  0u          // 512*26 float4        = 212992
#define OFF_XJP    212992u     // 512*13 pairs * 16B   = 106496 -> 319488
#define OFF_XC     319488u     // 512*3 f32            =   6144 -> 325632
#define OFF_EIDX   325632u     // 512*30 i32           =  61440 -> 387072
#define OFF_WSWZ   387072u     // 170*8*64 * 16B       = 1392640 -> 1779712
#define OFF_EPART  1779712u    // 2*15360*128 f32      = 15728640 -> 17508352

#define OUT_V     0
#define OUT_E     (NRES*NOUT)            // 65536
#define OUT_EIDX  (OUT_E + MTOT*NOUT)    // 2031616

typedef __attribute__((ext_vector_type(4))) float f32x4;

__device__ __forceinline__ unsigned short f2bf(float f) {
    unsigned u = __builtin_bit_cast(unsigned, f);
    return (unsigned short)((u + 0x7fffu + ((u >> 16) & 1u)) >> 16);
}
__device__ __forceinline__ float bflo(unsigned u) {
    return __builtin_bit_cast(float, u << 16);
}
__device__ __forceinline__ float bfhi(unsigned u) {
    return __builtin_bit_cast(float, u & 0xffff0000u);
}
__device__ __forceinline__ unsigned long long shfl_xor_u64(unsigned long long v, int m) {
    unsigned lo = (unsigned)v, hi = (unsigned)(v >> 32);
    lo = (unsigned)__shfl_xor((int)lo, m, 64);
    hi = (unsigned)__shfl_xor((int)hi, m, 64);
    return ((unsigned long long)hi << 32) | lo;
}

// ---------------------------------------------------------------- kernel A --
__global__ __launch_bounds__(128) void kA(
    const float* __restrict__ X, const float* __restrict__ Xm,
    const float* __restrict__ prot, const float* __restrict__ dna,
    const float* __restrict__ rna, const int* __restrict__ ptype,
    const float* __restrict__ Wn, const float* __restrict__ gn,
    const float* __restrict__ bn, char* __restrict__ ws,
    float* __restrict__ out)
{
    const int i = blockIdx.x, t = threadIdx.x;
    float4* augX4 = (float4*)(ws + OFF_AUGX4);
    float*  Xc    = (float*)(ws + OFF_XC);
    const float* Xi = X + i * 72;

    if (t < 26) {
        float x, y, z, mk;
        if (t < 24) {
            x = Xi[t*3]; y = Xi[t*3+1]; z = Xi[t*3+2];
            mk = Xm[i*24 + t];
        } else if (t == 24) {
            float b0 = Xi[3]-Xi[0], b1 = Xi[4]-Xi[1], b2 = Xi[5]-Xi[2];
            float c0 = Xi[6]-Xi[3], c1 = Xi[7]-Xi[4], c2 = Xi[8]-Xi[5];
            float a0 = b1*c2-b2*c1, a1 = b2*c0-b0*c2, a2 = b0*c1-b1*c0;
            x = -0.58273431f*a0 + 0.56802827f*b0 - 0.54067466f*c0 + Xi[3];
            y = -0.58273431f*a1 + 0.56802827f*b1 - 0.54067466f*c1 + Xi[4];
            z = -0.58273431f*a2 + 0.56802827f*b2 - 0.54067466f*c2 + Xi[5];
            mk = prot[i];
        } else {
            const float* O4 = Xi + 33; const float* C1 = Xi + 45; const float* C2 = Xi + 42;
            float b0 = C1[0]-O4[0], b1 = C1[1]-O4[1], b2 = C1[2]-O4[2];
            float c0 = C2[0]-C1[0], c1 = C2[1]-C1[1], c2 = C2[2]-C1[2];
            float a0 = b1*c2-b2*c1, a1 = b2*c0-b0*c2, a2 = b0*c1-b1*c0;
            x = -0.56967352f*a0 + 0.51055973f*b0 - 0.53122153f*c0 + C1[0];
            y = -0.56967352f*a1 + 0.51055973f*b1 - 0.53122153f*c1 + C1[1];
            z = -0.56967352f*a2 + 0.51055973f*b2 - 0.53122153f*c2 + C1[2];
            mk = dna[i] + rna[i];
        }
        augX4[i*26 + t] = make_float4(x, y, z, mk);
        uint2 pk;
        pk.x = (unsigned)f2bf(x) | ((unsigned)f2bf(y) << 16);
        pk.y = (unsigned)f2bf(z) | ((unsigned)f2bf(mk) << 16);
        *(uint2*)(ws + OFF_XJP + ((size_t)i*13 + (t>>1))*16 + (t&1)*8) = pk;
    } else if (t < 29) {
        int c = t - 26;
        Xc[i*3 + c] = Xi[3 + c] + Xi[45 + c];   // Ca + na_ref (C1')
    }

    __shared__ float red[4];
    int ty = ptype[i];
    float v = Wn[t*3 + ty];
    float s = v;
    #pragma unroll
    for (int off = 32; off; off >>= 1) s += __shfl_xor(s, off, 64);
    if ((t & 63) == 0) red[t>>6] = s;
    __syncthreads();
    float mean = (red[0] + red[1]) * (1.0f/128.0f);
    float d = v - mean;
    float s2 = d*d;
    #pragma unroll
    for (int off = 32; off; off >>= 1) s2 += __shfl_xor(s2, off, 64);
    if ((t & 63) == 0) red[2 + (t>>6)] = s2;
    __syncthreads();
    float var = (red[2] + red[3]) * (1.0f/128.0f);
    out[OUT_V + i*NOUT + t] = d * rsqrtf(var + 1e-5f) * gn[t] + bn[t];
}

// ---------------------------------------------------------------- kernel B --
__global__ __launch_bounds__(64) void kB(char* __restrict__ ws,
                                         float* __restrict__ out)
{
    const int i = blockIdx.x, l = threadIdx.x;
    const float* Xc = (const float*)(ws + OFF_XC);
    int* Eidx = (int*)(ws + OFF_EIDX);
    float xi0 = Xc[i*3], xi1 = Xc[i*3+1], xi2 = Xc[i*3+2];
    unsigned long long cand[8];
    #pragma unroll
    for (int s = 0; s < 8; s++) {
        int j = s*64 + l;
        float dx = xi0 - Xc[j*3], dy = xi1 - Xc[j*3+1], dz = xi2 - Xc[j*3+2];
        float dd = __fadd_rn(__fadd_rn(__fadd_rn(__fmul_rn(dx,dx), __fmul_rn(dy,dy)),
                                       __fmul_rn(dz,dz)), 1e-6f);
        float D = sqrtf(dd);
        cand[s] = ((unsigned long long)__builtin_bit_cast(unsigned, D) << 32) | (unsigned)j;
    }
    for (int m = 0; m < TOPK; m++) {
        unsigned long long k = cand[0];
        #pragma unroll
        for (int s = 1; s < 8; s++) if (cand[s] < k) k = cand[s];
        #pragma unroll
        for (int off = 32; off; off >>= 1) {
            unsigned long long o = shfl_xor_u64(k, off);
            if (o < k) k = o;
        }
        if (l == 0) {
            int j = (int)(k & 0xffffffffu);
            Eidx[i*TOPK + m] = j;
            out[OUT_EIDX + i*TOPK + m] = (float)j;
        }
        #pragma unroll
        for (int s = 0; s < 8; s++) if (cand[s] == k) cand[s] = ~0ull;
    }
}

// ---------------------------------------------------------------- kernel W --
// 16B unit f = (d*8 + nt)*64 + lane: for cc in {0,1}: slot s = 4d+2h+cc
// (h = lane>>5 quad-half), bytes j=0..7 = fp8 W[n=nt*16+(lane&15)]
// [feature fh*8+j of slot s], fh = (lane>>4)&1.
__global__ __launch_bounds__(256) void kW(const float* __restrict__ We,
                                          char* __restrict__ ws)
{
    int f = blockIdx.x*256 + threadIdx.x;           // 340*256 == 170*8*64
    int lane = f & 63, nt = (f >> 6) & 7, d = f >> 9;
    int n  = nt*16 + (lane & 15);
    int qd = lane >> 4, h = qd >> 1, fh = qd & 1;
    const float* Wrow = We + (size_t)n * KTOT;
    unsigned r[4];
    #pragma unroll
    for (int cc = 0; cc < 2; cc++) {
        int s = 4*d + 2*h + cc;
        float v[8];
        #pragma unroll
        for (int jj = 0; jj < 8; jj++) {
            int fc = fh*8 + jj;
            float x = 0.0f;
            if (s < 676)       x = Wrow[16 + s*16 + fc];
            else if (s == 676) x = Wrow[fc];
            v[jj] = x;
        }
        int lo = __builtin_amdgcn_cvt_pk_fp8_f32(v[0], v[1], 0, false);
        lo     = __builtin_amdgcn_cvt_pk_fp8_f32(v[2], v[3], lo, true);
        int hi = __builtin_amdgcn_cvt_pk_fp8_f32(v[4], v[5], 0, false);
        hi     = __builtin_amdgcn_cvt_pk_fp8_f32(v[6], v[7], hi, true);
        r[cc*2] = (unsigned)lo; r[cc*2+1] = (unsigned)hi;
    }
    ((uint4*)(ws + OFF_WSWZ))[f] = make_uint4(r[0], r[1], r[2], r[3]);
}

// ---------------------------------------------------------------- kernel C --
// 256 thr = 4 waves: wave w -> m-group mg=w&1 (16 rows), n-group ng=w>>1
// (4 n-tiles = 64 cols). blockIdx.x: 32-row tile; blockIdx.y: K half.
__global__ __launch_bounds__(256) void kC(const int* __restrict__ Ridx,
                                          const int* __restrict__ chain,
                                          const float* __restrict__ Wp,
                                          const float* __restrict__ bp,
                                          char* __restrict__ ws)
{
    const int mb = blockIdx.x, q = blockIdx.y;
    const int t = threadIdx.x, lane = t & 63, w = t >> 6;
    const int mlane = lane & 15, qd = lane >> 4;
    const int mg = w & 1, ng = w >> 1;
    const int h = qd >> 1, fh = qd & 1;

    const float4* augX4 = (const float4*)(ws + OFF_AUGX4);
    const uint4*  Xjp   = (const uint4*)(ws + OFF_XJP);
    const int*    Eidx  = (const int*)(ws + OFF_EIDX);
    const uint4*  gW    = (const uint4*)(ws + OFF_WSWZ);
    float*        Epart = (float*)(ws + OFF_EPART);

    __shared__ __align__(16) unsigned char Bsh[2][8192];

    const int row = mb*MB + mg*16 + mlane;     // row this lane generates A for
    const int i   = row / TOPK;
    const int j   = Eidx[row];

    int dcode;
    {
        int off  = Ridx[i] - Ridx[j];
        int same = (chain[i] == chain[j]);
        int dc = off + 32; dc = dc < 0 ? 0 : (dc > 64 ? 64 : dc);
        dcode = same ? dc : 65;
    }

    // exp(-((D-mu)/1.25)^2) = exp2(-(D*SA - mu*SA)^2)
    const float SA  = 0.96089792702915984f;
    const float MU0 = 1.9217958540583197f;
    const float MUS = 1.2811972360388798f;
    float muL[8];
    #pragma unroll
    for (int ff = 0; ff < 8; ff++) muL[ff] = MU0 + (float)(fh*8 + ff) * MUS;

    f32x4 acc[4];
    #pragma unroll
    for (int nn = 0; nn < 4; nn++) acc[nn] = (f32x4){0.f,0.f,0.f,0.f};

    const int d0 = q * DPB;

    // prologue: stage dcp d0 into Bsh[0] (wave w stages n-tiles 2w, 2w+1)
    {
        uint4 p0 = gW[(size_t)(d0*8 + 2*w  )*64 + lane];
        uint4 p1 = gW[(size_t)(d0*8 + 2*w+1)*64 + lane];
        ((uint4*)Bsh[0])[(2*w  )*64 + lane] = p0;
        ((uint4*)Bsh[0])[(2*w+1)*64 + lane] = p1;
    }

    for (int dd = 0; dd < DPB; dd++) {
        const int d = d0 + dd;
        const int dn = (dd == DPB-1) ? d : d + 1;

        // prefetch next B stage (global, no LDS hazard)
        uint4 nb0 = gW[(size_t)(dn*8 + 2*w  )*64 + lane];
        uint4 nb1 = gW[(size_t)(dn*8 + 2*w+1)*64 + lane];

        // ---- generate this lane's two A-frags (slots p0 = 4d+2h, p0+1) ----
        const int p0 = 4*d + 2*h;
        unsigned long long a0 = 0, a1 = 0;
        if (p0 < 676) {
            const int a  = p0 / 26;
            const int m2 = (p0 % 26) >> 1;
            float4 xi = augX4[i*26 + a];
            uint4  xp = Xjp[j*13 + m2];
            float e[16];
            #pragma unroll
            for (int cc = 0; cc < 2; cc++) {
                float jx, jy, jz, jm;
                if (cc == 0) { jx = bflo(xp.x); jy = bfhi(xp.x); jz = bflo(xp.y); jm = bfhi(xp.y); }
                else         { jx = bflo(xp.z); jy = bfhi(xp.z); jz = bflo(xp.w); jm = bfhi(xp.w); }
                float dx = xi.x - jx, dy = xi.y - jy, dz = xi.z - jz;
                float D  = sqrtf(dx*dx + dy*dy + dz*dz + 1e-6f);
                float Ds = D * SA;
                float ls = __log2f(xi.w * jm);   // 0 or -inf (masks are 0/1)
                #pragma unroll
                for (int ff = 0; ff < 8; ff++) {
                    float v = Ds - muL[ff];
                    e[cc*8 + ff] = exp2f(__builtin_fmaf(-v, v, ls));
                }
            }
            int r0 = __builtin_amdgcn_cvt_pk_fp8_f32(e[0], e[1], 0, false);
            r0     = __builtin_amdgcn_cvt_pk_fp8_f32(e[2], e[3], r0, true);
            int r1 = __builtin_amdgcn_cvt_pk_fp8_f32(e[4], e[5], 0, false);
            r1     = __builtin_amdgcn_cvt_pk_fp8_f32(e[6], e[7], r1, true);
            int r2 = __builtin_amdgcn_cvt_pk_fp8_f32(e[8], e[9], 0, false);
            r2     = __builtin_amdgcn_cvt_pk_fp8_f32(e[10], e[11], r2, true);
            int r3 = __builtin_amdgcn_cvt_pk_fp8_f32(e[12], e[13], 0, false);
            r3     = __builtin_amdgcn_cvt_pk_fp8_f32(e[14], e[15], r3, true);
            a0 = (unsigned long long)(unsigned)r0 | ((unsigned long long)(unsigned)r1 << 32);
            a1 = (unsigned long long)(unsigned)r2 | ((unsigned long long)(unsigned)r3 << 32);
        } else if (p0 == 676) {
            float e[8];
            #pragma unroll
            for (int ff = 0; ff < 8; ff++) {
                int fc = fh*8 + ff;
                e[ff] = Wp[fc*66 + dcode] + bp[fc];
            }
            int r0 = __builtin_amdgcn_cvt_pk_fp8_f32(e[0], e[1], 0, false);
            r0     = __builtin_amdgcn_cvt_pk_fp8_f32(e[2], e[3], r0, true);
            int r1 = __builtin_amdgcn_cvt_pk_fp8_f32(e[4], e[5], 0, false);
            r1     = __builtin_amdgcn_cvt_pk_fp8_f32(e[6], e[7], r1, true);
            a0 = (unsigned long long)(unsigned)r0 | ((unsigned long long)(unsigned)r1 << 32);
        }

        __syncthreads();   // prev-iter readers done; Bsh[dd&1] staged & visible

        // stage next buffer
        ((uint4*)Bsh[(dd+1)&1])[(2*w  )*64 + lane] = nb0;
        ((uint4*)Bsh[(dd+1)&1])[(2*w+1)*64 + lane] = nb1;

        // MFMA: 4 n-tiles x 2 chunks
        const uint4* Bb = (const uint4*)Bsh[dd & 1];
        #pragma unroll
        for (int nn = 0; nn < 4; nn++) {
            uint4 bq = Bb[(ng*4 + nn)*64 + lane];
            unsigned long long b0 = (unsigned long long)bq.x | ((unsigned long long)bq.y << 32);
            unsigned long long b1 = (unsigned long long)bq.z | ((unsigned long long)bq.w << 32);
            acc[nn] = __builtin_amdgcn_mfma_f32_16x16x32_fp8_fp8((long)a0, (long)b0, acc[nn], 0, 0, 0);
            acc[nn] = __builtin_amdgcn_mfma_f32_16x16x32_fp8_fp8((long)a1, (long)b1, acc[nn], 0, 0, 0);
        }
    }

    // epilogue: f32 partials. C/D: col = lane&15, row = qd*4 + rr.
    #pragma unroll
    for (int nn = 0; nn < 4; nn++) {
        int col = (ng*4 + nn)*16 + mlane;
        #pragma unroll
        for (int rr = 0; rr < 4; rr++) {
            int grow = mb*MB + mg*16 + qd*4 + rr;
            Epart[((size_t)q*MTOT + grow)*NOUT + col] = acc[nn][rr];
        }
    }
}

// ---------------------------------------------------------------- kernel D --
__global__ __launch_bounds__(512) void kD(const float* __restrict__ ge,
                                          const float* __restrict__ be,
                                          char* __restrict__ ws,
                                          float* __restrict__ out)
{
    const float* Ep = (const float*)(ws + OFF_EPART);
    const int t = threadIdx.x, rl = t >> 7, col = t & 127;
    const int row = blockIdx.x*4 + rl;
    size_t b = (size_t)row*NOUT + col;
    float v = Ep[b] + Ep[(size_t)MTOT*NOUT + b];

    __shared__ float red[8][2];
    float s = v, q2 = v*v;
    #pragma unroll
    for (int off = 32; off; off >>= 1) {
        s  += __shfl_xor(s,  off, 64);
        q2 += __shfl_xor(q2, off, 64);
    }
    if ((t & 63) == 0) { red[t>>6][0] = s; red[t>>6][1] = q2; }
    __syncthreads();
    float S = red[2*rl][0] + red[2*rl+1][0];
    float Q = red[2*rl][1] + red[2*rl+1][1];
    float mean = S * (1.0f/128.0f);
    float var  = Q * (1.0f/128.0f) - mean*mean;
    float rstd = rsqrtf(var + 1e-5f);
    out[OUT_E + (size_t)row*NOUT + col] = (v - mean) * rstd * ge[col] + be[col];
}

// ------------------------------------------------------------------- launch --
extern "C" void kernel_launch(void* const* d_in, const int* in_sizes, int n_in,
                              void* d_out, int out_size, void* d_ws, size_t ws_size,
                              hipStream_t stream)
{
    const float* X     = (const float*)d_in[0];
    const int*   Ridx  = (const int*)d_in[2];
    const int*   chain = (const int*)d_in[3];
    const float* Xm    = (const float*)d_in[4];
    const float* prot  = (const float*)d_in[5];
    const float* dna   = (const float*)d_in[6];
    const float* rna   = (const float*)d_in[7];
    const int*   ptype = (const int*)d_in[8];
    const float* Wp    = (const float*)d_in[9];
    const float* bp    = (const float*)d_in[10];
    const float* We    = (const float*)d_in[11];
    const float* Wn    = (const float*)d_in[12];
    const float* ge    = (const float*)d_in[13];
    const float* be    = (const float*)d_in[14];
    const float* gn    = (const float*)d_in[15];
    const float* bn    = (const float*)d_in[16];
    char* ws = (char*)d_ws;
    float* out = (float*)d_out;

    kW<<<dim3(340), dim3(256), 0, stream>>>(We, ws);
    kA<<<dim3(NRES), dim3(128), 0, stream>>>(X, Xm, prot, dna, rna, ptype, Wn, gn, bn, ws, out);
    kB<<<dim3(NRES), dim3(64), 0, stream>>>(ws, out);
    kC<<<dim3(MTOT/MB, KSPLIT), dim3(256), 0, stream>>>(Ridx, chain, Wp, bp, ws);
    kD<<<dim3(MTOT/4), dim3(512), 0, stream>>>(ge, be, ws, out);
}

// Round 5
// 202.904 us; speedup vs baseline: 1.9343x; 1.4444x over previous
//
#include <hip/hip_runtime.h>
#include <stdint.h>

// ---------------------------------------------------------------------------
// ProteinFeaturesNA on MI355X — R5: dedup A-gen (wave = 16 rows x 128 cols),
// no-LDS barrier-free K-loop, raw transcendentals, incremental slot state.
// Outputs (f32, concat): V[512][128], E[15360][128], E_idx[15360].
//
//  kA: aug atoms -> float4 (x,y,z,mask), Xc, V layernorm.
//  kB: top-30 neighbors (packed u64 wave min) -> Eidx + out.
//  kW: W_edge -> fp8 B-fragments (slot order: 0..675 RBF, 676 positional,
//      677..679 zero). Same fragment mapping as R4 (verified).
//  kC: 256 thr = 4 independent waves; wave w: rows bx*64+w*16..+15, all 128
//      cols, K-half q. A-frags in registers (8 exp2/chunk/lane), B straight
//      from global (L2-resident), zero LDS, zero barriers. f32 partials.
//  kD: reduce 2 K-partials + layernorm -> E.
// ---------------------------------------------------------------------------

#define NRES   512
#define TOPK   30
#define NATOM  26
#define KTOT   10832
#define NDCP   170            // 64-k double-chunks (padded K = 10880)
#define MTOT   (NRES*TOPK)    // 15360
#define NOUT   128
#define KSPLIT 2
#define DPB    (NDCP/KSPLIT)  // 85

#define OFF_AUGX4  0u          // 512*26 float4   = 212992
#define OFF_XC     212992u     // 512*3 f32       =   6144 -> 219136
#define OFF_EIDX   219136u     // 512*30 i32      =  61440 -> 280576
#define OFF_WSWZ   280576u     // 170*8*64 * 16B  = 1392640 -> 1673216
#define OFF_EPART  1673216u    // 2*15360*128 f32 = 15728640 -> 17401856

#define OUT_V     0
#define OUT_E     (NRES*NOUT)            // 65536
#define OUT_EIDX  (OUT_E + MTOT*NOUT)    // 2031616

typedef __attribute__((ext_vector_type(4))) float f32x4;

__device__ __forceinline__ unsigned long long shfl_xor_u64(unsigned long long v, int m) {
    unsigned lo = (unsigned)v, hi = (unsigned)(v >> 32);
    lo = (unsigned)__shfl_xor((int)lo, m, 64);
    hi = (unsigned)__shfl_xor((int)hi, m, 64);
    return ((unsigned long long)hi << 32) | lo;
}

// raw HW transcendentals (no libm denormal guards — fp8 output can't see them)
__device__ __forceinline__ float fexp2(float x) { return __builtin_amdgcn_exp2f(x); }
__device__ __forceinline__ float fsqrtf(float x) { return __builtin_amdgcn_sqrtf(x); }

// one 8-feature RBF chunk -> 8 packed fp8 bytes
__device__ __forceinline__ unsigned long long gen8(float4 xi, float4 xj,
                                                   const float* muL, float SA) {
    float s  = xi.w * xj.w;                       // 0 or 1
    float dx = xi.x - xj.x, dy = xi.y - xj.y, dz = xi.z - xj.z;
    float d2 = __builtin_fmaf(dx, dx, __builtin_fmaf(dy, dy,
               __builtin_fmaf(dz, dz, 1e-6f)));
    float Ds = fsqrtf(d2) * SA;
    Ds = (s == 0.0f) ? 1.0e3f : Ds;               // masked -> all features 0
    float e[8];
    #pragma unroll
    for (int ff = 0; ff < 8; ff++) {
        float v = Ds - muL[ff];
        e[ff] = fexp2(-(v * v));
    }
    int r0 = __builtin_amdgcn_cvt_pk_fp8_f32(e[0], e[1], 0, false);
    r0     = __builtin_amdgcn_cvt_pk_fp8_f32(e[2], e[3], r0, true);
    int r1 = __builtin_amdgcn_cvt_pk_fp8_f32(e[4], e[5], 0, false);
    r1     = __builtin_amdgcn_cvt_pk_fp8_f32(e[6], e[7], r1, true);
    return (unsigned long long)(unsigned)r0 | ((unsigned long long)(unsigned)r1 << 32);
}

// ---------------------------------------------------------------- kernel A --
__global__ __launch_bounds__(128) void kA(
    const float* __restrict__ X, const float* __restrict__ Xm,
    const float* __restrict__ prot, const float* __restrict__ dna,
    const float* __restrict__ rna, const int* __restrict__ ptype,
    const float* __restrict__ Wn, const float* __restrict__ gn,
    const float* __restrict__ bn, char* __restrict__ ws,
    float* __restrict__ out)
{
    const int i = blockIdx.x, t = threadIdx.x;
    float4* augX4 = (float4*)(ws + OFF_AUGX4);
    float*  Xc    = (float*)(ws + OFF_XC);
    const float* Xi = X + i * 72;

    if (t < 26) {
        float x, y, z, mk;
        if (t < 24) {
            x = Xi[t*3]; y = Xi[t*3+1]; z = Xi[t*3+2];
            mk = Xm[i*24 + t];
        } else if (t == 24) {
            float b0 = Xi[3]-Xi[0], b1 = Xi[4]-Xi[1], b2 = Xi[5]-Xi[2];
            float c0 = Xi[6]-Xi[3], c1 = Xi[7]-Xi[4], c2 = Xi[8]-Xi[5];
            float a0 = b1*c2-b2*c1, a1 = b2*c0-b0*c2, a2 = b0*c1-b1*c0;
            x = -0.58273431f*a0 + 0.56802827f*b0 - 0.54067466f*c0 + Xi[3];
            y = -0.58273431f*a1 + 0.56802827f*b1 - 0.54067466f*c1 + Xi[4];
            z = -0.58273431f*a2 + 0.56802827f*b2 - 0.54067466f*c2 + Xi[5];
            mk = prot[i];
        } else {
            const float* O4 = Xi + 33; const float* C1 = Xi + 45; const float* C2 = Xi + 42;
            float b0 = C1[0]-O4[0], b1 = C1[1]-O4[1], b2 = C1[2]-O4[2];
            float c0 = C2[0]-C1[0], c1 = C2[1]-C1[1], c2 = C2[2]-C1[2];
            float a0 = b1*c2-b2*c1, a1 = b2*c0-b0*c2, a2 = b0*c1-b1*c0;
            x = -0.56967352f*a0 + 0.51055973f*b0 - 0.53122153f*c0 + C1[0];
            y = -0.56967352f*a1 + 0.51055973f*b1 - 0.53122153f*c1 + C1[1];
            z = -0.56967352f*a2 + 0.51055973f*b2 - 0.53122153f*c2 + C1[2];
            mk = dna[i] + rna[i];
        }
        augX4[i*26 + t] = make_float4(x, y, z, mk);
    } else if (t < 29) {
        int c = t - 26;
        Xc[i*3 + c] = Xi[3 + c] + Xi[45 + c];   // Ca + na_ref (C1')
    }

    __shared__ float red[4];
    int ty = ptype[i];
    float v = Wn[t*3 + ty];
    float s = v;
    #pragma unroll
    for (int off = 32; off; off >>= 1) s += __shfl_xor(s, off, 64);
    if ((t & 63) == 0) red[t>>6] = s;
    __syncthreads();
    float mean = (red[0] + red[1]) * (1.0f/128.0f);
    float d = v - mean;
    float s2 = d*d;
    #pragma unroll
    for (int off = 32; off; off >>= 1) s2 += __shfl_xor(s2, off, 64);
    if ((t & 63) == 0) red[2 + (t>>6)] = s2;
    __syncthreads();
    float var = (red[2] + red[3]) * (1.0f/128.0f);
    out[OUT_V + i*NOUT + t] = d * rsqrtf(var + 1e-5f) * gn[t] + bn[t];
}

// ---------------------------------------------------------------- kernel B --
__global__ __launch_bounds__(64) void kB(char* __restrict__ ws,
                                         float* __restrict__ out)
{
    const int i = blockIdx.x, l = threadIdx.x;
    const float* Xc = (const float*)(ws + OFF_XC);
    int* Eidx = (int*)(ws + OFF_EIDX);
    float xi0 = Xc[i*3], xi1 = Xc[i*3+1], xi2 = Xc[i*3+2];
    unsigned long long cand[8];
    #pragma unroll
    for (int s = 0; s < 8; s++) {
        int j = s*64 + l;
        float dx = xi0 - Xc[j*3], dy = xi1 - Xc[j*3+1], dz = xi2 - Xc[j*3+2];
        float dd = __fadd_rn(__fadd_rn(__fadd_rn(__fmul_rn(dx,dx), __fmul_rn(dy,dy)),
                                       __fmul_rn(dz,dz)), 1e-6f);
        float D = sqrtf(dd);
        cand[s] = ((unsigned long long)__builtin_bit_cast(unsigned, D) << 32) | (unsigned)j;
    }
    for (int m = 0; m < TOPK; m++) {
        unsigned long long k = cand[0];
        #pragma unroll
        for (int s = 1; s < 8; s++) if (cand[s] < k) k = cand[s];
        #pragma unroll
        for (int off = 32; off; off >>= 1) {
            unsigned long long o = shfl_xor_u64(k, off);
            if (o < k) k = o;
        }
        if (l == 0) {
            int j = (int)(k & 0xffffffffu);
            Eidx[i*TOPK + m] = j;
            out[OUT_EIDX + i*TOPK + m] = (float)j;
        }
        #pragma unroll
        for (int s = 0; s < 8; s++) if (cand[s] == k) cand[s] = ~0ull;
    }
}

// ---------------------------------------------------------------- kernel W --
// 16B unit f = (d*8 + nt)*64 + lane: for cc in {0,1}: slot s = 4d+2h+cc
// (h = (lane>>5)), bytes j=0..7 = fp8 W[n=nt*16+(lane&15)]
// [feature fh*8+j of slot s], fh = (lane>>4)&1.  Same mapping as R4.
__global__ __launch_bounds__(256) void kW(const float* __restrict__ We,
                                          char* __restrict__ ws)
{
    int f = blockIdx.x*256 + threadIdx.x;           // 340*256 == 170*8*64
    int lane = f & 63, nt = (f >> 6) & 7, d = f >> 9;
    int n  = nt*16 + (lane & 15);
    int qd = lane >> 4, h = qd >> 1, fh = qd & 1;
    const float* Wrow = We + (size_t)n * KTOT;
    unsigned r[4];
    #pragma unroll
    for (int cc = 0; cc < 2; cc++) {
        int s = 4*d + 2*h + cc;
        float v[8];
        #pragma unroll
        for (int jj = 0; jj < 8; jj++) {
            int fc = fh*8 + jj;
            float x = 0.0f;
            if (s < 676)       x = Wrow[16 + s*16 + fc];
            else if (s == 676) x = Wrow[fc];
            v[jj] = x;
        }
        int lo = __builtin_amdgcn_cvt_pk_fp8_f32(v[0], v[1], 0, false);
        lo     = __builtin_amdgcn_cvt_pk_fp8_f32(v[2], v[3], lo, true);
        int hi = __builtin_amdgcn_cvt_pk_fp8_f32(v[4], v[5], 0, false);
        hi     = __builtin_amdgcn_cvt_pk_fp8_f32(v[6], v[7], hi, true);
        r[cc*2] = (unsigned)lo; r[cc*2+1] = (unsigned)hi;
    }
    ((uint4*)(ws + OFF_WSWZ))[f] = make_uint4(r[0], r[1], r[2], r[3]);
}

// ---------------------------------------------------------------- kernel C --
// 4 independent waves per block; wave w: 16 rows (bx*64+w*16+mlane), all 128
// cols, K-half q. No LDS, no barriers.
__global__ __launch_bounds__(256, 1) void kC(const int* __restrict__ Ridx,
                                             const int* __restrict__ chain,
                                             const float* __restrict__ Wp,
                                             const float* __restrict__ bp,
                                             char* __restrict__ ws)
{
    const int bx = blockIdx.x, q = blockIdx.y;
    const int t = threadIdx.x, lane = t & 63, w = t >> 6;
    const int mlane = lane & 15, qd = lane >> 4;
    const int h = qd >> 1, fh = qd & 1;

    const float4* augX4 = (const float4*)(ws + OFF_AUGX4);
    const int*    Eidx  = (const int*)(ws + OFF_EIDX);
    const uint4*  gW    = (const uint4*)(ws + OFF_WSWZ);
    float*        Epart = (float*)(ws + OFF_EPART);

    const int row = bx*64 + w*16 + mlane;      // this lane's A row
    const int i   = row / TOPK;
    const int j   = Eidx[row];

    int dcode;
    {
        int off  = Ridx[i] - Ridx[j];
        int same = (chain[i] == chain[j]);
        int dc = off + 32; dc = dc < 0 ? 0 : (dc > 64 ? 64 : dc);
        dcode = same ? dc : 65;
    }

    const float SA  = 0.96089792702915984f;    // sqrt(log2 e)/1.25
    const float MU0 = 1.9217958540583197f;     // 2*SA
    const float MUS = 1.2811972360388798f;     // (4/3)*SA
    float muL[8];
    #pragma unroll
    for (int ff = 0; ff < 8; ff++) muL[ff] = MU0 + (float)(fh*8 + ff) * MUS;

    const float4* Ai = augX4 + i*26;
    const float4* Aj = augX4 + j*26;

    f32x4 acc[8];
    #pragma unroll
    for (int nt = 0; nt < 8; nt++) acc[nt] = (f32x4){0.f,0.f,0.f,0.f};

    // incremental slot state: slot p0 = 4d + 2h = a*26 + rem (rem even)
    // d0 = 85q -> p0 = 340q + 2h = (13q)*26 + (2q + 2h)
    int a = q*13, rem = 2*h + 2*q;
    float4 xi  = Ai[a];
    float4 xj0 = Aj[rem];
    float4 xj1 = Aj[rem + 1];

    const int d0 = q * DPB;
    const int nmain = DPB - q;                 // q=0: 85 (all RBF); q=1: 84 + tail

    for (int dd = 0; dd < nmain; dd++) {
        const int d = d0 + dd;

        // B fragments for this d (L1/L2-resident; consumed ~300 cyc later)
        uint4 b[8];
        #pragma unroll
        for (int nt = 0; nt < 8; nt++)
            b[nt] = gW[(size_t)(d*8 + nt)*64 + lane];

        // next-iter state + coordinate prefetch (used next iteration)
        int remn = rem + 4;
        int an   = a + (remn >= 26 ? 1 : 0);
        remn     = (remn >= 26) ? remn - 26 : remn;
        float4 xin  = Ai[an];
        float4 xj0n = Aj[remn];
        float4 xj1n = Aj[remn + 1];

        // A fragments: chunk0 = slot p0 (j-atom rem), chunk1 = p0+1 (rem+1)
        unsigned long long a0 = gen8(xi, xj0, muL, SA);
        unsigned long long a1 = gen8(xi, xj1, muL, SA);

        #pragma unroll
        for (int nt = 0; nt < 8; nt++) {
            unsigned long long b0 = (unsigned long long)b[nt].x | ((unsigned long long)b[nt].y << 32);
            unsigned long long b1 = (unsigned long long)b[nt].z | ((unsigned long long)b[nt].w << 32);
            acc[nt] = __builtin_amdgcn_mfma_f32_16x16x32_fp8_fp8((long)a0, (long)b0, acc[nt], 0, 0, 0);
            acc[nt] = __builtin_amdgcn_mfma_f32_16x16x32_fp8_fp8((long)a1, (long)b1, acc[nt], 0, 0, 0);
        }

        xi = xin; xj0 = xj0n; xj1 = xj1n; a = an; rem = remn;
    }

    if (q == 1) {
        // tail d = 169: slots 676 (positional, h=0) / 677..679 (zero)
        const int d = 169;
        uint4 b[8];
        #pragma unroll
        for (int nt = 0; nt < 8; nt++)
            b[nt] = gW[(size_t)(d*8 + nt)*64 + lane];

        float e[8];
        #pragma unroll
        for (int ff = 0; ff < 8; ff++) {
            int fc = fh*8 + ff;
            float v = Wp[fc*66 + dcode] + bp[fc];
            e[ff] = (h == 0) ? v : 0.0f;
        }
        int r0 = __builtin_amdgcn_cvt_pk_fp8_f32(e[0], e[1], 0, false);
        r0     = __builtin_amdgcn_cvt_pk_fp8_f32(e[2], e[3], r0, true);
        int r1 = __builtin_amdgcn_cvt_pk_fp8_f32(e[4], e[5], 0, false);
        r1     = __builtin_amdgcn_cvt_pk_fp8_f32(e[6], e[7], r1, true);
        unsigned long long a0 = (unsigned long long)(unsigned)r0 | ((unsigned long long)(unsigned)r1 << 32);
        unsigned long long a1 = 0;

        #pragma unroll
        for (int nt = 0; nt < 8; nt++) {
            unsigned long long b0 = (unsigned long long)b[nt].x | ((unsigned long long)b[nt].y << 32);
            unsigned long long b1 = (unsigned long long)b[nt].z | ((unsigned long long)b[nt].w << 32);
            acc[nt] = __builtin_amdgcn_mfma_f32_16x16x32_fp8_fp8((long)a0, (long)b0, acc[nt], 0, 0, 0);
            acc[nt] = __builtin_amdgcn_mfma_f32_16x16x32_fp8_fp8((long)a1, (long)b1, acc[nt], 0, 0, 0);
        }
    }

    // epilogue: f32 partials. D layout: col = lane&15, row = qd*4 + rr (as R4)
    #pragma unroll
    for (int nt = 0; nt < 8; nt++) {
        int col = nt*16 + mlane;
        #pragma unroll
        for (int rr = 0; rr < 4; rr++) {
            int grow = bx*64 + w*16 + qd*4 + rr;
            Epart[((size_t)q*MTOT + grow)*NOUT + col] = acc[nt][rr];
        }
    }
}

// ---------------------------------------------------------------- kernel D --
__global__ __launch_bounds__(512) void kD(const float* __restrict__ ge,
                                          const float* __restrict__ be,
                                          char* __restrict__ ws,
                                          float* __restrict__ out)
{
    const float* Ep = (const float*)(ws + OFF_EPART);
    const int t = threadIdx.x, rl = t >> 7, col = t & 127;
    const int row = blockIdx.x*4 + rl;
    size_t b = (size_t)row*NOUT + col;
    float v = Ep[b] + Ep[(size_t)MTOT*NOUT + b];

    __shared__ float red[8][2];
    float s = v, q2 = v*v;
    #pragma unroll
    for (int off = 32; off; off >>= 1) {
        s  += __shfl_xor(s,  off, 64);
        q2 += __shfl_xor(q2, off, 64);
    }
    if ((t & 63) == 0) { red[t>>6][0] = s; red[t>>6][1] = q2; }
    __syncthreads();
    float S = red[2*rl][0] + red[2*rl+1][0];
    float Q = red[2*rl][1] + red[2*rl+1][1];
    float mean = S * (1.0f/128.0f);
    float var  = Q * (1.0f/128.0f) - mean*mean;
    float rstd = rsqrtf(var + 1e-5f);
    out[OUT_E + (size_t)row*NOUT + col] = (v - mean) * rstd * ge[col] + be[col];
}

// ------------------------------------------------------------------- launch --
extern "C" void kernel_launch(void* const* d_in, const int* in_sizes, int n_in,
                              void* d_out, int out_size, void* d_ws, size_t ws_size,
                              hipStream_t stream)
{
    const float* X     = (const float*)d_in[0];
    const int*   Ridx  = (const int*)d_in[2];
    const int*   chain = (const int*)d_in[3];
    const float* Xm    = (const float*)d_in[4];
    const float* prot  = (const float*)d_in[5];
    const float* dna   = (const float*)d_in[6];
    const float* rna   = (const float*)d_in[7];
    const int*   ptype = (const int*)d_in[8];
    const float* Wp    = (const float*)d_in[9];
    const float* bp    = (const float*)d_in[10];
    const float* We    = (const float*)d_in[11];
    const float* Wn    = (const float*)d_in[12];
    const float* ge    = (const float*)d_in[13];
    const float* be    = (const float*)d_in[14];
    const float* gn    = (const float*)d_in[15];
    const float* bn    = (const float*)d_in[16];
    char* ws = (char*)d_ws;
    float* out = (float*)d_out;

    kW<<<dim3(340), dim3(256), 0, stream>>>(We, ws);
    kA<<<dim3(NRES), dim3(128), 0, stream>>>(X, Xm, prot, dna, rna, ptype, Wn, gn, bn, ws, out);
    kB<<<dim3(NRES), dim3(64), 0, stream>>>(ws, out);
    kC<<<dim3(MTOT/64, KSPLIT), dim3(256), 0, stream>>>(Ridx, chain, Wp, bp, ws);
    kD<<<dim3(MTOT/4), dim3(512), 0, stream>>>(ge, be, ws, out);
}

// Round 6
// 198.524 us; speedup vs baseline: 1.9769x; 1.0221x over previous
//
#include <hip/hip_runtime.h>
#include <stdint.h>

// ---------------------------------------------------------------------------
// ProteinFeaturesNA on MI355X — R6: exp2-chained RBF, KSPLIT=4 (bf16 partials),
// coalesced kW, merged kA+kB.
// Outputs (f32, concat): V[512][128], E[15360][128], E_idx[15360].
// ---------------------------------------------------------------------------

#define NRES   512
#define TOPK   30
#define NATOM  26
#define KTOT   10832
#define NDCP   170            // 64-k double-chunks (padded K = 10880)
#define MTOT   (NRES*TOPK)    // 15360
#define NOUT   128
#define KSPLIT 4

#define OFF_AUGX4  0u          // 512*26 float4   = 212992
#define OFF_EIDX   212992u     // 512*30 i32      =  61440 -> 274432
#define OFF_WSWZ   274432u     // 170*8*64 * 16B  = 1392640 -> 1667072
#define OFF_EPART  1667072u    // 4*15360*128 bf16 = 15728640 -> 17395712

#define OUT_V     0
#define OUT_E     (NRES*NOUT)            // 65536
#define OUT_EIDX  (OUT_E + MTOT*NOUT)    // 2031616

typedef __attribute__((ext_vector_type(4))) float f32x4;

#define SA_C   0.96089792702915984f     // sqrt(log2 e)/1.25
#define MU0_C  1.9217958540583197f      // 2*SA
#define MUS_C  1.2811972360388798f      // (4/3)*SA

__device__ __forceinline__ unsigned short f2bf(float f) {
    unsigned u = __builtin_bit_cast(unsigned, f);
    return (unsigned short)((u + 0x7fffu + ((u >> 16) & 1u)) >> 16);
}
__device__ __forceinline__ float bf2f(unsigned short u) {
    return __builtin_bit_cast(float, (unsigned)u << 16);
}
__device__ __forceinline__ unsigned long long shfl_xor_u64(unsigned long long v, int m) {
    unsigned lo = (unsigned)v, hi = (unsigned)(v >> 32);
    lo = (unsigned)__shfl_xor((int)lo, m, 64);
    hi = (unsigned)__shfl_xor((int)hi, m, 64);
    return ((unsigned long long)hi << 32) | lo;
}
__device__ __forceinline__ float fexp2(float x) { return __builtin_amdgcn_exp2f(x); }
__device__ __forceinline__ float fsqrtf(float x) { return __builtin_amdgcn_sqrtf(x); }

// 8 RBF features (window start fh*8) via center-chain: 3 exp2 + 12 mul.
__device__ __forceinline__ unsigned long long gen8c(float4 xi, float4 xj,
                                                    float mu3, float CC) {
    float s  = xi.w * xj.w;                       // 0 or 1
    float dx = xi.x - xj.x, dy = xi.y - xj.y, dz = xi.z - xj.z;
    float d2 = __builtin_fmaf(dx, dx, __builtin_fmaf(dy, dy,
               __builtin_fmaf(dz, dz, 1e-6f)));
    float Ds = fsqrtf(d2) * SA_C;
    Ds = fminf(Ds, 45.0f);                        // keeps ratio exp2 args < 128
    Ds = (s == 0.0f) ? 45.0f : Ds;                // masked -> all features 0
    float u  = Ds - mu3;                          // center = local feature 3
    float e3 = fexp2(-(u * u));
    float r  = fexp2(__builtin_fmaf( 2.0f*MUS_C, u, -(MUS_C*MUS_C)));
    float sd = fexp2(__builtin_fmaf(-2.0f*MUS_C, u, -(MUS_C*MUS_C)));
    float e4 = e3*r;  r  *= CC;
    float e5 = e4*r;  r  *= CC;
    float e6 = e5*r;  r  *= CC;
    float e7 = e6*r;
    float e2 = e3*sd; sd *= CC;
    float e1 = e2*sd; sd *= CC;
    float e0 = e1*sd;
    int r0 = __builtin_amdgcn_cvt_pk_fp8_f32(e0, e1, 0, false);
    r0     = __builtin_amdgcn_cvt_pk_fp8_f32(e2, e3, r0, true);
    int r1 = __builtin_amdgcn_cvt_pk_fp8_f32(e4, e5, 0, false);
    r1     = __builtin_amdgcn_cvt_pk_fp8_f32(e6, e7, r1, true);
    return (unsigned long long)(unsigned)r0 | ((unsigned long long)(unsigned)r1 << 32);
}

// --------------------------------------------------------------- kernel AB --
// Block i: aug atoms + V layernorm (128 thr), then wave 0 does top-30
// (Xc computed inline from X — bit-identical ops to previous passing version).
__global__ __launch_bounds__(128) void kAB(
    const float* __restrict__ X, const float* __restrict__ Xm,
    const float* __restrict__ prot, const float* __restrict__ dna,
    const float* __restrict__ rna, const int* __restrict__ ptype,
    const float* __restrict__ Wn, const float* __restrict__ gn,
    const float* __restrict__ bn, char* __restrict__ ws,
    float* __restrict__ out)
{
    const int i = blockIdx.x, t = threadIdx.x;
    float4* augX4 = (float4*)(ws + OFF_AUGX4);
    int*    Eidx  = (int*)(ws + OFF_EIDX);
    const float* Xi = X + i * 72;

    if (t < 26) {
        float x, y, z, mk;
        if (t < 24) {
            x = Xi[t*3]; y = Xi[t*3+1]; z = Xi[t*3+2];
            mk = Xm[i*24 + t];
        } else if (t == 24) {
            float b0 = Xi[3]-Xi[0], b1 = Xi[4]-Xi[1], b2 = Xi[5]-Xi[2];
            float c0 = Xi[6]-Xi[3], c1 = Xi[7]-Xi[4], c2 = Xi[8]-Xi[5];
            float a0 = b1*c2-b2*c1, a1 = b2*c0-b0*c2, a2 = b0*c1-b1*c0;
            x = -0.58273431f*a0 + 0.56802827f*b0 - 0.54067466f*c0 + Xi[3];
            y = -0.58273431f*a1 + 0.56802827f*b1 - 0.54067466f*c1 + Xi[4];
            z = -0.58273431f*a2 + 0.56802827f*b2 - 0.54067466f*c2 + Xi[5];
            mk = prot[i];
        } else {
            const float* O4 = Xi + 33; const float* C1 = Xi + 45; const float* C2 = Xi + 42;
            float b0 = C1[0]-O4[0], b1 = C1[1]-O4[1], b2 = C1[2]-O4[2];
            float c0 = C2[0]-C1[0], c1 = C2[1]-C1[1], c2 = C2[2]-C1[2];
            float a0 = b1*c2-b2*c1, a1 = b2*c0-b0*c2, a2 = b0*c1-b1*c0;
            x = -0.56967352f*a0 + 0.51055973f*b0 - 0.53122153f*c0 + C1[0];
            y = -0.56967352f*a1 + 0.51055973f*b1 - 0.53122153f*c1 + C1[1];
            z = -0.56967352f*a2 + 0.51055973f*b2 - 0.53122153f*c2 + C1[2];
            mk = dna[i] + rna[i];
        }
        augX4[i*26 + t] = make_float4(x, y, z, mk);
    }

    // V layernorm (all 128 threads)
    __shared__ float red[4];
    int ty = ptype[i];
    float v = Wn[t*3 + ty];
    float s = v;
    #pragma unroll
    for (int off = 32; off; off >>= 1) s += __shfl_xor(s, off, 64);
    if ((t & 63) == 0) red[t>>6] = s;
    __syncthreads();
    float mean = (red[0] + red[1]) * (1.0f/128.0f);
    float d = v - mean;
    float s2 = d*d;
    #pragma unroll
    for (int off = 32; off; off >>= 1) s2 += __shfl_xor(s2, off, 64);
    if ((t & 63) == 0) red[2 + (t>>6)] = s2;
    __syncthreads();
    float var = (red[2] + red[3]) * (1.0f/128.0f);
    out[OUT_V + i*NOUT + t] = d * rsqrtf(var + 1e-5f) * gn[t] + bn[t];

    // top-30 (wave 0 only); Xc[j] = Ca[j] + C1'[j] computed inline
    if (t >= 64) return;
    const int l = t;
    float xi0 = Xi[3] + Xi[45], xi1 = Xi[4] + Xi[46], xi2 = Xi[5] + Xi[47];
    unsigned long long cand[8];
    #pragma unroll
    for (int sg = 0; sg < 8; sg++) {
        int j = sg*64 + l;
        const float* Xj = X + j*72;
        float c0 = Xj[3] + Xj[45], c1 = Xj[4] + Xj[46], c2 = Xj[5] + Xj[47];
        float dx = xi0 - c0, dy = xi1 - c1, dz = xi2 - c2;
        float dd = __fadd_rn(__fadd_rn(__fadd_rn(__fmul_rn(dx,dx), __fmul_rn(dy,dy)),
                                       __fmul_rn(dz,dz)), 1e-6f);
        float D = sqrtf(dd);
        cand[sg] = ((unsigned long long)__builtin_bit_cast(unsigned, D) << 32) | (unsigned)j;
    }
    for (int m = 0; m < TOPK; m++) {
        unsigned long long k = cand[0];
        #pragma unroll
        for (int sg = 1; sg < 8; sg++) if (cand[sg] < k) k = cand[sg];
        #pragma unroll
        for (int off = 32; off; off >>= 1) {
            unsigned long long o = shfl_xor_u64(k, off);
            if (o < k) k = o;
        }
        if (l == 0) {
            int j = (int)(k & 0xffffffffu);
            Eidx[i*TOPK + m] = j;
            out[OUT_EIDX + i*TOPK + m] = (float)j;
        }
        #pragma unroll
        for (int sg = 0; sg < 8; sg++) if (cand[sg] == k) cand[sg] = ~0ull;
    }
}

// ---------------------------------------------------------------- kernel W --
// Coalesced: thread = (slot s, row n); reads 16 consecutive floats, writes
// two 8-B fragment pieces. Fragment byte (d,nt,lane,cc,j) <-> W[n][k]:
// n = nt*16+(lane&15); slot = 4d + 2*(lane>>5) + cc; feat = ((lane>>4)&1)*8+j.
__global__ __launch_bounds__(256) void kW(const float* __restrict__ We,
                                          char* __restrict__ ws)
{
    int s = blockIdx.x*256 + threadIdx.x;      // grid (3, 128); s in [0,677)
    int n = blockIdx.y;
    if (s >= 677) return;
    const float* src = We + (size_t)n*KTOT + ((s < 676) ? (16 + s*16) : 0);
    float4 v0 = ((const float4*)src)[0];
    float4 v1 = ((const float4*)src)[1];
    float4 v2 = ((const float4*)src)[2];
    float4 v3 = ((const float4*)src)[3];

    int d = s >> 2, hc = s & 3, h = hc >> 1, cc = hc & 1;
    size_t base = OFF_WSWZ + ((size_t)(d*8 + (n >> 4))*64)*16 + (size_t)cc*8;
    {   // fh = 0: feats 0..7
        int r0 = __builtin_amdgcn_cvt_pk_fp8_f32(v0.x, v0.y, 0, false);
        r0     = __builtin_amdgcn_cvt_pk_fp8_f32(v0.z, v0.w, r0, true);
        int r1 = __builtin_amdgcn_cvt_pk_fp8_f32(v1.x, v1.y, 0, false);
        r1     = __builtin_amdgcn_cvt_pk_fp8_f32(v1.z, v1.w, r1, true);
        int lane = h*32 + (n & 15);
        *(uint2*)(ws + base + (size_t)lane*16) = make_uint2((unsigned)r0, (unsigned)r1);
    }
    {   // fh = 1: feats 8..15
        int r0 = __builtin_amdgcn_cvt_pk_fp8_f32(v2.x, v2.y, 0, false);
        r0     = __builtin_amdgcn_cvt_pk_fp8_f32(v2.z, v2.w, r0, true);
        int r1 = __builtin_amdgcn_cvt_pk_fp8_f32(v3.x, v3.y, 0, false);
        r1     = __builtin_amdgcn_cvt_pk_fp8_f32(v3.z, v3.w, r1, true);
        int lane = h*32 + 16 + (n & 15);
        *(uint2*)(ws + base + (size_t)lane*16) = make_uint2((unsigned)r0, (unsigned)r1);
    }
}

// ---------------------------------------------------------------- kernel C --
// grid (240, 4): block = 4 waves, 64 rows, K quarter q. Wave w: rows
// bx*64+w*16+mlane, all 128 cols. No LDS, no barriers. bf16 partials.
__global__ __launch_bounds__(256) void kC(const int* __restrict__ Ridx,
                                          const int* __restrict__ chain,
                                          const float* __restrict__ Wp,
                                          const float* __restrict__ bp,
                                          char* __restrict__ ws)
{
    const int bx = blockIdx.x, q = blockIdx.y;
    const int t = threadIdx.x, lane = t & 63, w = t >> 6;
    const int mlane = lane & 15, qd = lane >> 4;
    const int h = qd >> 1, fh = qd & 1;

    const float4* augX4 = (const float4*)(ws + OFF_AUGX4);
    const int*    Eidx  = (const int*)(ws + OFF_EIDX);
    const uint4*  gW    = (const uint4*)(ws + OFF_WSWZ);
    unsigned short* Ep  = (unsigned short*)(ws + OFF_EPART)
                        + (size_t)q * MTOT * NOUT;

    const int row = bx*64 + w*16 + mlane;
    const int i   = row / TOPK;
    const int j   = Eidx[row];

    int dcode;
    {
        int off  = Ridx[i] - Ridx[j];
        int same = (chain[i] == chain[j]);
        int dc = off + 32; dc = dc < 0 ? 0 : (dc > 64 ? 64 : dc);
        dcode = same ? dc : 65;
    }

    const float mu3 = MU0_C + (float)(fh*8 + 3) * MUS_C;   // window center
    const float CC  = fexp2(-2.0f * MUS_C * MUS_C);

    const float4* Ai = augX4 + i*26;
    const float4* Aj = augX4 + j*26;

    f32x4 acc[8];
    #pragma unroll
    for (int nt = 0; nt < 8; nt++) acc[nt] = (f32x4){0.f,0.f,0.f,0.f};

    // K partition: d0 = {0,43,86,128}, main iters = {43,43,42,41}(+tail q=3)
    const int d0    = (q == 0) ? 0 : (q == 1) ? 43 : (q == 2) ? 86 : 128;
    const int nmain = (q <  2) ? 43 : (q == 2) ? 42 : 41;

    // slot state: p0 = 4*d + 2h = a*26 + rem
    int p0s = 4*d0 + 2*h;
    int a = p0s / 26, rem = p0s - a*26;
    float4 xi  = Ai[a];
    float4 xj0 = Aj[rem];
    float4 xj1 = Aj[rem + 1];

    const uint4* Wb = gW + (size_t)d0*512 + lane;

    for (int dd = 0; dd < nmain; dd++) {
        uint4 b[8];
        #pragma unroll
        for (int nt = 0; nt < 8; nt++) b[nt] = Wb[nt*64];
        Wb += 512;

        // next-iter state + coordinate prefetch
        int remn = rem + 4;
        int an   = a + (remn >= 26 ? 1 : 0);
        remn     = (remn >= 26) ? remn - 26 : remn;
        float4 xin  = Ai[an];
        float4 xj0n = Aj[remn];
        float4 xj1n = Aj[remn + 1];

        unsigned long long a0 = gen8c(xi, xj0, mu3, CC);
        unsigned long long a1 = gen8c(xi, xj1, mu3, CC);

        #pragma unroll
        for (int nt = 0; nt < 8; nt++) {
            unsigned long long b0 = (unsigned long long)b[nt].x | ((unsigned long long)b[nt].y << 32);
            unsigned long long b1 = (unsigned long long)b[nt].z | ((unsigned long long)b[nt].w << 32);
            acc[nt] = __builtin_amdgcn_mfma_f32_16x16x32_fp8_fp8((long)a0, (long)b0, acc[nt], 0, 0, 0);
            acc[nt] = __builtin_amdgcn_mfma_f32_16x16x32_fp8_fp8((long)a1, (long)b1, acc[nt], 0, 0, 0);
        }

        xi = xin; xj0 = xj0n; xj1 = xj1n; a = an; rem = remn;
    }

    if (q == 3) {   // tail d=169: slots 676 (positional, h=0) / 677..679 (zero)
        uint4 b[8];
        #pragma unroll
        for (int nt = 0; nt < 8; nt++) b[nt] = Wb[nt*64];

        unsigned long long a0 = 0, a1 = 0;
        if (h == 0) {
            float e[8];
            #pragma unroll
            for (int ff = 0; ff < 8; ff++) {
                int fc = fh*8 + ff;
                e[ff] = Wp[fc*66 + dcode] + bp[fc];
            }
            int r0 = __builtin_amdgcn_cvt_pk_fp8_f32(e[0], e[1], 0, false);
            r0     = __builtin_amdgcn_cvt_pk_fp8_f32(e[2], e[3], r0, true);
            int r1 = __builtin_amdgcn_cvt_pk_fp8_f32(e[4], e[5], 0, false);
            r1     = __builtin_amdgcn_cvt_pk_fp8_f32(e[6], e[7], r1, true);
            a0 = (unsigned long long)(unsigned)r0 | ((unsigned long long)(unsigned)r1 << 32);
        }
        #pragma unroll
        for (int nt = 0; nt < 8; nt++) {
            unsigned long long b0 = (unsigned long long)b[nt].x | ((unsigned long long)b[nt].y << 32);
            unsigned long long b1 = (unsigned long long)b[nt].z | ((unsigned long long)b[nt].w << 32);
            acc[nt] = __builtin_amdgcn_mfma_f32_16x16x32_fp8_fp8((long)a0, (long)b0, acc[nt], 0, 0, 0);
            acc[nt] = __builtin_amdgcn_mfma_f32_16x16x32_fp8_fp8((long)a1, (long)b1, acc[nt], 0, 0, 0);
        }
    }

    // epilogue: bf16 partials. D layout: col = lane&15, row = qd*4 + rr.
    #pragma unroll
    for (int nt = 0; nt < 8; nt++) {
        int col = nt*16 + mlane;
        #pragma unroll
        for (int rr = 0; rr < 4; rr++) {
            int grow = bx*64 + w*16 + qd*4 + rr;
            Ep[(size_t)grow*NOUT + col] = f2bf(acc[nt][rr]);
        }
    }
}

// ---------------------------------------------------------------- kernel D --
__global__ __launch_bounds__(512) void kD(const float* __restrict__ ge,
                                          const float* __restrict__ be,
                                          char* __restrict__ ws,
                                          float* __restrict__ out)
{
    const unsigned short* Ep = (const unsigned short*)(ws + OFF_EPART);
    const int t = threadIdx.x, rl = t >> 7, col = t & 127;
    const int row = blockIdx.x*4 + rl;
    const size_t stride = (size_t)MTOT * NOUT;
    size_t b = (size_t)row*NOUT + col;
    float v = bf2f(Ep[b]) + bf2f(Ep[b + stride])
            + bf2f(Ep[b + 2*stride]) + bf2f(Ep[b + 3*stride]);

    __shared__ float red[8][2];
    float s = v, q2 = v*v;
    #pragma unroll
    for (int off = 32; off; off >>= 1) {
        s  += __shfl_xor(s,  off, 64);
        q2 += __shfl_xor(q2, off, 64);
    }
    if ((t & 63) == 0) { red[t>>6][0] = s; red[t>>6][1] = q2; }
    __syncthreads();
    float S = red[2*rl][0] + red[2*rl+1][0];
    float Q = red[2*rl][1] + red[2*rl+1][1];
    float mean = S * (1.0f/128.0f);
    float var  = Q * (1.0f/128.0f) - mean*mean;
    float rstd = rsqrtf(var + 1e-5f);
    out[OUT_E + (size_t)row*NOUT + col] = (v - mean) * rstd * ge[col] + be[col];
}

// ------------------------------------------------------------------- launch --
extern "C" void kernel_launch(void* const* d_in, const int* in_sizes, int n_in,
                              void* d_out, int out_size, void* d_ws, size_t ws_size,
                              hipStream_t stream)
{
    const float* X     = (const float*)d_in[0];
    const int*   Ridx  = (const int*)d_in[2];
    const int*   chain = (const int*)d_in[3];
    const float* Xm    = (const float*)d_in[4];
    const float* prot  = (const float*)d_in[5];
    const float* dna   = (const float*)d_in[6];
    const float* rna   = (const float*)d_in[7];
    const int*   ptype = (const int*)d_in[8];
    const float* Wp    = (const float*)d_in[9];
    const float* bp    = (const float*)d_in[10];
    const float* We    = (const float*)d_in[11];
    const float* Wn    = (const float*)d_in[12];
    const float* ge    = (const float*)d_in[13];
    const float* be    = (const float*)d_in[14];
    const float* gn    = (const float*)d_in[15];
    const float* bn    = (const float*)d_in[16];
    char* ws = (char*)d_ws;
    float* out = (float*)d_out;

    kW<<<dim3(3, 128), dim3(256), 0, stream>>>(We, ws);
    kAB<<<dim3(NRES), dim3(128), 0, stream>>>(X, Xm, prot, dna, rna, ptype, Wn, gn, bn, ws, out);
    kC<<<dim3(MTOT/64, KSPLIT), dim3(256), 0, stream>>>(Ridx, chain, Wp, bp, ws);
    kD<<<dim3(MTOT/4), dim3(512), 0, stream>>>(ge, be, ws, out);
}